// Round 8
// baseline (1408.943 us; speedup 1.0000x reference)
//
#include <hip/hip_runtime.h>
#include <math.h>

// Archetipes RNN scan: T=256 sequential steps, M=16 modules, H=256, I=128.
// R15 = R14 (proven 1190 us) + speculative stage issue + pipelined poll.
// R14 post-mortem: prediction matched (hop-count model now 3x validated).
// Remaining 4.43 us/step = mean chain ~2.9 (visibility 0.3 + detect 0.65
// [poll period ~1 RT, serialized load->compare->reload] + stage RT 0.5 +
// compute ~1.3) + ~1.3 straggler spread (max over 256 blocks; each wake
// adds poll quantization + a full serialized stage RT).
// Changes vs R14:
//  1. SPECULATIVE STAGE ISSUE: the 4 dense stage loads are hoisted ABOVE
//     the detect/spin. The existing embedded-tag retry loop (already
//     correctness-bearing in R14) decides fresh/stale at wake. Late
//     blocks (the critical-path ones) find their speculative data fresh
//     -> post-wake stage RT vanishes. Early blocks reload, overlapped
//     with other blocks' compute. Never worse than load-at-wake. Cost:
//     one extra 32KB LLC read round per block per step (LLC-class BW,
//     flags remain the detection medium -> poll traffic unchanged).
//  2. PIPELINED 2-DEEP FLAG POLL (wave0): keep two poll batches in
//     flight; evaluate A while B flies. Detection granularity drops from
//     ~1 RT (~450ns) to evaluate spacing (~60ns): less delay, less jitter.
// Kept byte-for-byte: replicated flag lines g_done (R14), LDS s_go
// fan-out (R14), coalesced column publish via s_pub (R12), padded LDS
// HP=260 (R10, verified), dense staging + tags (R9), weights register-
// resident (R3), conn-sparsity olist (R4), LDS out-buffer + single flush
// (R7), ONE barrier/step, epoch-monotone tags (graph-replay safe).

#define DT_C    0.042f
#define GAMMA_C 2.7f
#define EPS_C   4.7f

constexpr int M = 16, H = 256, I = 128, T = 256;
constexpr int HP = H + 4;     // padded LDS row stride (16B-aligned, 2-way banks)
constexpr int NROW = M * H;   // 4096 packets per slot
constexpr int NBLK = 256;
constexpr int NTHR = 1024;    // 16 waves
constexpr int NREPF = 16;     // flag replica arrays (1 KB each)

typedef float f32x4 __attribute__((ext_vector_type(4)));
typedef unsigned long long u64;
typedef unsigned int u32;

// Slot s (s=0..T) = hy after s steps. Packet = (tag<<32)|float_bits,
// tag = base + s + 1. Flat index p = h*16 + m.
__device__ __align__(64) u64 g_hy[(size_t)(T + 1) * NROW];   // 8.4 MB
__device__ __align__(64) u32 g_done[NREPF][NBLK];            // 16 x 1 KB
__device__ u32 g_epoch;

__global__ __launch_bounds__(NTHR) void rnn_persistent(
    const float* __restrict__ x,      // T*I
    const float* __restrict__ wm,     // M*M*H*H
    const float* __restrict__ conn,   // M*M
    const float* __restrict__ mask,   // M
    const float* __restrict__ W_in,   // M*H*I
    const float* __restrict__ W_rec,  // M*H*H
    const float* __restrict__ bias,   // M*H
    float* __restrict__ out)          // T*M*2*H state_seq, then T*M*H fb_seq
{
  const int h    = blockIdx.x;
  const int tid  = threadIdx.x;
  const int m    = tid >> 6;      // wave = module
  const int lane = tid & 63;

  __shared__ float hy_lds[2][M * HP];   // 2 x 16.25 KB, layout [m][h] padded
  __shared__ float outb_hz[T][M];       // 16 KB
  __shared__ float outb_fb[T][M];       // 16 KB
  __shared__ u64   s_pub[M];            // publish gather (tagged packets)
  __shared__ float s_c[M * M];
  __shared__ float s_scal[M];
  __shared__ int   s_olist[M][M];
  __shared__ float s_oc[M][M];
  __shared__ int   s_ocnt[M];
  __shared__ u32   s_base;
  __shared__ u32   s_go;                // monotone step flag (wave0 -> all)

  if (tid == 0) {
    s_base = __hip_atomic_load(&g_epoch, __ATOMIC_RELAXED, __HIP_MEMORY_SCOPE_AGENT);
    s_go = 0;
  }
  if (tid < M) s_pub[tid] = 0ull;
  if (tid < M * M) s_c[tid] = conn[tid];
  __syncthreads();

  // ---- publish slot 0 = zeros + flags ASAP (before heavy weight loads) ----
  const u32 base = s_base;
  if (tid < M) {
    const u64 pkt0 = ((u64)(base + 1u) << 32);   // hy = 0.0f, tag = base+1
    __hip_atomic_store(&g_hy[(size_t)h * M + tid], pkt0,
                       __ATOMIC_RELAXED, __HIP_MEMORY_SCOPE_AGENT);
  }
  if (tid < NREPF)
    __hip_atomic_store(&g_done[tid][h], base + 1u,
                       __ATOMIC_RELAXED, __HIP_MEMORY_SCOPE_AGENT);

  if (tid < M) {
    float s = 0.f; int cnt = 0;
    for (int o = 0; o < M; ++o) {
      float c = s_c[tid * M + o];
      s += c;
      if (c != 0.f) { s_olist[tid][cnt] = o; s_oc[tid][cnt] = c; ++cnt; }
    }
    for (int k = cnt; k < M; ++k) { s_olist[tid][k] = 0; s_oc[tid][k] = 0.f; }
    s_ocnt[tid] = cnt;
    s_scal[tid] = 1.0f / fmaxf(s, 1.0f);
  }
  __syncthreads();

  const int   rowg  = m * H + h;    // global row (bias/W_rec/W_in)
  const float maskm = mask[m];
  const float biasv = bias[rowg];
  const float scal  = s_scal[m];
  const int   ocnt  = s_ocnt[m];

  // ---- one-time: weights into registers (conn pre-applied) ----
  f32x4 wreg[M];
#pragma unroll
  for (int k = 0; k < M; ++k) {
    if (k < ocnt) {
      const int o = s_olist[m][k];
      const f32x4 wv = *reinterpret_cast<const f32x4*>(
          wm + ((size_t)(m * M + o) * H + h) * H + 4 * lane);
      wreg[k] = wv * s_oc[m][k];
    } else {
      wreg[k] = (f32x4)0.f;
    }
  }
  const f32x4  wrec = *reinterpret_cast<const f32x4*>(W_rec + (size_t)rowg * H + 4 * lane);
  const float2 win  = *reinterpret_cast<const float2*>(W_in + (size_t)rowg * I + 2 * lane);

  float hz = 0.f;
  // x[0] prefetch (per-lane slice; same for every wave)
  float2 xd = *reinterpret_cast<const float2*>(x + 2 * lane);

  const int  mcol = (tid & 15) * HP;   // staging LDS column base
  const int  hrow = tid >> 4;          // staging LDS row (0..63)
  int buf = 0;

  for (int t = 0; t < T; ++t) {
    const u32 tgt = base + (u32)t + 1u;
    const u64* src = g_hy + (size_t)t * NROW + tid;

    // ---- speculative stage issue (validated at wake; never worse) ----
    u64 a0 = __hip_atomic_load(src,        __ATOMIC_RELAXED, __HIP_MEMORY_SCOPE_AGENT);
    u64 a1 = __hip_atomic_load(src + 1024, __ATOMIC_RELAXED, __HIP_MEMORY_SCOPE_AGENT);
    u64 a2 = __hip_atomic_load(src + 2048, __ATOMIC_RELAXED, __HIP_MEMORY_SCOPE_AGENT);
    u64 a3 = __hip_atomic_load(src + 3072, __ATOMIC_RELAXED, __HIP_MEMORY_SCOPE_AGENT);

    // ---- detect: wave0 pipelined flag poll (2-deep), LDS fan-out ----
    if (m == 0) {
      const u32* fp = &g_done[h & (NREPF - 1)][0] + lane;
      // batch A in flight
      u32 c0 = __hip_atomic_load(fp,       __ATOMIC_RELAXED, __HIP_MEMORY_SCOPE_AGENT);
      u32 c1 = __hip_atomic_load(fp + 64,  __ATOMIC_RELAXED, __HIP_MEMORY_SCOPE_AGENT);
      u32 c2 = __hip_atomic_load(fp + 128, __ATOMIC_RELAXED, __HIP_MEMORY_SCOPE_AGENT);
      u32 c3 = __hip_atomic_load(fp + 192, __ATOMIC_RELAXED, __HIP_MEMORY_SCOPE_AGENT);
      for (;;) {
        // issue batch B before evaluating A
        const u32 d0 = __hip_atomic_load(fp,       __ATOMIC_RELAXED, __HIP_MEMORY_SCOPE_AGENT);
        const u32 d1 = __hip_atomic_load(fp + 64,  __ATOMIC_RELAXED, __HIP_MEMORY_SCOPE_AGENT);
        const u32 d2 = __hip_atomic_load(fp + 128, __ATOMIC_RELAXED, __HIP_MEMORY_SCOPE_AGENT);
        const u32 d3 = __hip_atomic_load(fp + 192, __ATOMIC_RELAXED, __HIP_MEMORY_SCOPE_AGENT);
        if (__all((c0 >= tgt) & (c1 >= tgt) & (c2 >= tgt) & (c3 >= tgt))) break;
        // issue batch A' before evaluating B
        c0 = __hip_atomic_load(fp,       __ATOMIC_RELAXED, __HIP_MEMORY_SCOPE_AGENT);
        c1 = __hip_atomic_load(fp + 64,  __ATOMIC_RELAXED, __HIP_MEMORY_SCOPE_AGENT);
        c2 = __hip_atomic_load(fp + 128, __ATOMIC_RELAXED, __HIP_MEMORY_SCOPE_AGENT);
        c3 = __hip_atomic_load(fp + 192, __ATOMIC_RELAXED, __HIP_MEMORY_SCOPE_AGENT);
        if (__all((d0 >= tgt) & (d1 >= tgt) & (d2 >= tgt) & (d3 >= tgt))) break;
      }
      if (lane == 0)
        __hip_atomic_store(&s_go, (u32)(t + 1), __ATOMIC_RELAXED,
                           __HIP_MEMORY_SCOPE_WORKGROUP);
    } else {
      while (__hip_atomic_load(&s_go, __ATOMIC_RELAXED,
                               __HIP_MEMORY_SCOPE_WORKGROUP) < (u32)(t + 1)) { }
    }
    asm volatile("" ::: "memory");

    // ---- validate speculative data; reload only if stale ----
    {
      while (!((((u32)(a0 >> 32)) >= tgt) & (((u32)(a1 >> 32)) >= tgt) &
               (((u32)(a2 >> 32)) >= tgt) & (((u32)(a3 >> 32)) >= tgt))) {
        a0 = __hip_atomic_load(src,        __ATOMIC_RELAXED, __HIP_MEMORY_SCOPE_AGENT);
        a1 = __hip_atomic_load(src + 1024, __ATOMIC_RELAXED, __HIP_MEMORY_SCOPE_AGENT);
        a2 = __hip_atomic_load(src + 2048, __ATOMIC_RELAXED, __HIP_MEMORY_SCOPE_AGENT);
        a3 = __hip_atomic_load(src + 3072, __ATOMIC_RELAXED, __HIP_MEMORY_SCOPE_AGENT);
      }
      float* dst = &hy_lds[buf][0];
      // packet p = tid + 1024k: module = tid&15, column = hrow + 64k
      dst[mcol + hrow      ] = __uint_as_float((u32)a0);
      dst[mcol + hrow +  64] = __uint_as_float((u32)a1);
      dst[mcol + hrow + 128] = __uint_as_float((u32)a2);
      dst[mcol + hrow + 192] = __uint_as_float((u32)a3);
    }
    __syncthreads();   // ONLY barrier per step; prev publish ack drains here

    // input term (xd prefetched last iteration)
    float acc_o = win.x * (maskm * xd.x);
    acc_o = fmaf(win.y, maskm * xd.y, acc_o);
    // recurrent term
    {
      const f32x4 hp = *reinterpret_cast<const f32x4*>(&hy_lds[buf][m * HP + 4 * lane]);
      acc_o = fmaf(wrec.x, hp.x, acc_o);
      acc_o = fmaf(wrec.y, hp.y, acc_o);
      acc_o = fmaf(wrec.z, hp.z, acc_o);
      acc_o = fmaf(wrec.w, hp.w, acc_o);
    }
    // feedback: register weights x LDS hy fragments
    float acc_fb = 0.f;
#pragma unroll
    for (int k = 0; k < M; ++k) {
      if (k < ocnt) {
        const int o = s_olist[m][k];
        const f32x4 hp = *reinterpret_cast<const f32x4*>(&hy_lds[buf][o * HP + 4 * lane]);
        float po = wreg[k].x * hp.x;
        po = fmaf(wreg[k].y, hp.y, po);
        po = fmaf(wreg[k].z, hp.z, po);
        po = fmaf(wreg[k].w, hp.w, po);
        acc_fb += po;
      }
    }

    // wave-wide butterfly reduce
    for (int off = 32; off > 0; off >>= 1) {
      acc_fb += __shfl_xor(acc_fb, off);
      acc_o  += __shfl_xor(acc_o,  off);
    }

    if (lane == 0) {
      const float fb   = scal * acc_fb;
      const float hy_p = hy_lds[buf][m * HP + h];
      const float pre  = acc_o + biasv + fb;
      const float hz_n = hz + DT_C * (tanhf(pre) - GAMMA_C * hy_p - EPS_C * hz);
      const float hy_n = hy_p + DT_C * hz_n;
      hz = hz_n;
      // drop tagged packet in LDS; wave0 publishes the whole column
      const u64 pkt = ((u64)(tgt + 1u) << 32) | (u64)__float_as_uint(hy_n);
      __hip_atomic_store(&s_pub[m], pkt, __ATOMIC_RELAXED,
                         __HIP_MEMORY_SCOPE_WORKGROUP);
      // buffer hz/fb in LDS; flushed once after the loop
      outb_hz[t][m] = hz_n;
      outb_fb[t][m] = fb;
    }
    asm volatile("" ::: "memory");

    // ---- wave0: gather 16 packets, ONE coalesced store, then flags ----
    if (m == 0) {
      u64 p;
      for (;;) {
        p = __hip_atomic_load(&s_pub[lane & 15], __ATOMIC_RELAXED,
                              __HIP_MEMORY_SCOPE_WORKGROUP);
        if (__all(((u32)(p >> 32)) >= tgt + 1u)) break;
      }
      if (lane < M)
        __hip_atomic_store(&g_hy[(size_t)(t + 1) * NROW + (size_t)h * M + lane],
                           p, __ATOMIC_RELAXED, __HIP_MEMORY_SCOPE_AGENT);
      // replicated completion flags (hint; tags validated by consumers)
      if (lane < NREPF)
        __hip_atomic_store(&g_done[lane][h], tgt + 1u,
                           __ATOMIC_RELAXED, __HIP_MEMORY_SCOPE_AGENT);
    }

    if (t + 1 < T)
      xd = *reinterpret_cast<const float2*>(x + (size_t)(t + 1) * I + 2 * lane);
    buf ^= 1;
  }

  __syncthreads();   // outb_* visible; final publishes drained (vmcnt(0))

  // ---- one-time flush: hy from own g_hy slots, hz/fb from LDS ----
  const size_t fb_base = (size_t)T * M * 2 * H;
  for (int i = tid; i < T * M; i += NTHR) {
    const int t  = i >> 4;
    const int mm = i & 15;
    const u64 q = __hip_atomic_load(
        &g_hy[(size_t)(t + 1) * NROW + (size_t)h * M + mm],
        __ATOMIC_RELAXED, __HIP_MEMORY_SCOPE_AGENT);
    const float hyv = __uint_as_float((u32)q);
    const size_t so = (size_t)t * (M * 2 * H) + (size_t)mm * (2 * H);
    out[so + h]     = hyv;
    out[so + H + h] = outb_hz[t][mm];
    out[fb_base + (size_t)t * (M * H) + (size_t)mm * H + h] = outb_fb[t][mm];
  }

  // epoch bump for next launch/replay: strictly above every tag used here
  if (h == 0 && tid == 0)
    __hip_atomic_store(&g_epoch, base + (u32)(T + 2),
                       __ATOMIC_RELAXED, __HIP_MEMORY_SCOPE_AGENT);
}

extern "C" void kernel_launch(void* const* d_in, const int* in_sizes, int n_in,
                              void* d_out, int out_size, void* d_ws, size_t ws_size,
                              hipStream_t stream) {
  const float* x     = (const float*)d_in[0];
  const float* wm    = (const float*)d_in[1];
  const float* conn  = (const float*)d_in[2];
  const float* mask  = (const float*)d_in[3];
  const float* W_in  = (const float*)d_in[4];
  const float* W_rec = (const float*)d_in[5];
  const float* bias  = (const float*)d_in[6];

  rnn_persistent<<<NBLK, NTHR, 0, stream>>>(
      x, wm, conn, mask, W_in, W_rec, bias, (float*)d_out);
}

// Round 9
// 1188.073 us; speedup vs baseline: 1.1859x; 1.1859x over previous
//
#include <hip/hip_runtime.h>
#include <math.h>

// Archetipes RNN scan: T=256 sequential steps, M=16 modules, H=256, I=128.
// R17 = R14 (proven 1190 us) + pipelined 2-deep flag poll + s_sleep in the
// LDS fan-out spin. Speculative staging REVERTED.
// R15 post-mortem: speculation regressed (1409 us, FETCH 72->121 MB). The
// loop-top speculative loads are issued pre-publish -> almost always stale
// -> full reload anyway PLUS an extra 32KB read round per block per step
// that congested the LLC exactly when publishes needed it. Lesson: with an
// all-to-all rendezvous in the LLC, any non-useful traffic near the
// critical moment taxes everyone's critical path.
// Changes vs R14:
//  1. PIPELINED 2-DEEP FLAG POLL (wave0): keep two poll batches in flight,
//     evaluate A while B flies. Detection quantization drops from ~1 LLC
//     RT (~450ns) to the evaluate spacing. Cost: 2x poll reads on 16 lines
//     from only 16 wave0s/replica - negligible traffic.
//  2. s_sleep(1) IN THE s_go SPIN (waves 1..15): the tight LDS spin was
//     stealing ~3/4 of wave0's SIMD issue slots (4 waves/SIMD) during the
//     latency-critical poll/compare and stage-issue sequences.
// Kept byte-for-byte from R14: replicated flag lines g_done (plain stores,
// distinct addresses), wave0-only global poll + LDS s_go fan-out, stage at
// wake with embedded-tag validation retry (flags are a hint, tags are
// ground truth), coalesced column publish via s_pub (R12), padded LDS
// HP=260 (R10, verified), dense staging (R9), weights register-resident
// (R3), conn-sparsity olist (R4), LDS out-buffer + single flush (R7),
// ONE barrier/step, epoch-monotone tags (graph-replay safe).

#define DT_C    0.042f
#define GAMMA_C 2.7f
#define EPS_C   4.7f

constexpr int M = 16, H = 256, I = 128, T = 256;
constexpr int HP = H + 4;     // padded LDS row stride (16B-aligned, 2-way banks)
constexpr int NROW = M * H;   // 4096 packets per slot
constexpr int NBLK = 256;
constexpr int NTHR = 1024;    // 16 waves
constexpr int NREPF = 16;     // flag replica arrays (1 KB each)

typedef float f32x4 __attribute__((ext_vector_type(4)));
typedef unsigned long long u64;
typedef unsigned int u32;

// Slot s (s=0..T) = hy after s steps. Packet = (tag<<32)|float_bits,
// tag = base + s + 1. Flat index p = h*16 + m.
__device__ __align__(64) u64 g_hy[(size_t)(T + 1) * NROW];   // 8.4 MB
__device__ __align__(64) u32 g_done[NREPF][NBLK];            // 16 x 1 KB
__device__ u32 g_epoch;

__global__ __launch_bounds__(NTHR) void rnn_persistent(
    const float* __restrict__ x,      // T*I
    const float* __restrict__ wm,     // M*M*H*H
    const float* __restrict__ conn,   // M*M
    const float* __restrict__ mask,   // M
    const float* __restrict__ W_in,   // M*H*I
    const float* __restrict__ W_rec,  // M*H*H
    const float* __restrict__ bias,   // M*H
    float* __restrict__ out)          // T*M*2*H state_seq, then T*M*H fb_seq
{
  const int h    = blockIdx.x;
  const int tid  = threadIdx.x;
  const int m    = tid >> 6;      // wave = module
  const int lane = tid & 63;

  __shared__ float hy_lds[2][M * HP];   // 2 x 16.25 KB, layout [m][h] padded
  __shared__ float outb_hz[T][M];       // 16 KB
  __shared__ float outb_fb[T][M];       // 16 KB
  __shared__ u64   s_pub[M];            // publish gather (tagged packets)
  __shared__ float s_c[M * M];
  __shared__ float s_scal[M];
  __shared__ int   s_olist[M][M];
  __shared__ float s_oc[M][M];
  __shared__ int   s_ocnt[M];
  __shared__ u32   s_base;
  __shared__ u32   s_go;                // monotone step flag (wave0 -> all)

  if (tid == 0) {
    s_base = __hip_atomic_load(&g_epoch, __ATOMIC_RELAXED, __HIP_MEMORY_SCOPE_AGENT);
    s_go = 0;
  }
  if (tid < M) s_pub[tid] = 0ull;
  if (tid < M * M) s_c[tid] = conn[tid];
  __syncthreads();

  // ---- publish slot 0 = zeros + flags ASAP (before heavy weight loads) ----
  const u32 base = s_base;
  if (tid < M) {
    const u64 pkt0 = ((u64)(base + 1u) << 32);   // hy = 0.0f, tag = base+1
    __hip_atomic_store(&g_hy[(size_t)h * M + tid], pkt0,
                       __ATOMIC_RELAXED, __HIP_MEMORY_SCOPE_AGENT);
  }
  if (tid < NREPF)
    __hip_atomic_store(&g_done[tid][h], base + 1u,
                       __ATOMIC_RELAXED, __HIP_MEMORY_SCOPE_AGENT);

  if (tid < M) {
    float s = 0.f; int cnt = 0;
    for (int o = 0; o < M; ++o) {
      float c = s_c[tid * M + o];
      s += c;
      if (c != 0.f) { s_olist[tid][cnt] = o; s_oc[tid][cnt] = c; ++cnt; }
    }
    for (int k = cnt; k < M; ++k) { s_olist[tid][k] = 0; s_oc[tid][k] = 0.f; }
    s_ocnt[tid] = cnt;
    s_scal[tid] = 1.0f / fmaxf(s, 1.0f);
  }
  __syncthreads();

  const int   rowg  = m * H + h;    // global row (bias/W_rec/W_in)
  const float maskm = mask[m];
  const float biasv = bias[rowg];
  const float scal  = s_scal[m];
  const int   ocnt  = s_ocnt[m];

  // ---- one-time: weights into registers (conn pre-applied) ----
  f32x4 wreg[M];
#pragma unroll
  for (int k = 0; k < M; ++k) {
    if (k < ocnt) {
      const int o = s_olist[m][k];
      const f32x4 wv = *reinterpret_cast<const f32x4*>(
          wm + ((size_t)(m * M + o) * H + h) * H + 4 * lane);
      wreg[k] = wv * s_oc[m][k];
    } else {
      wreg[k] = (f32x4)0.f;
    }
  }
  const f32x4  wrec = *reinterpret_cast<const f32x4*>(W_rec + (size_t)rowg * H + 4 * lane);
  const float2 win  = *reinterpret_cast<const float2*>(W_in + (size_t)rowg * I + 2 * lane);

  float hz = 0.f;
  // x[0] prefetch (per-lane slice; same for every wave)
  float2 xd = *reinterpret_cast<const float2*>(x + 2 * lane);

  const int  mcol = (tid & 15) * HP;   // staging LDS column base
  const int  hrow = tid >> 4;          // staging LDS row (0..63)
  int buf = 0;

  for (int t = 0; t < T; ++t) {
    const u32 tgt = base + (u32)t + 1u;

    // ---- detect: wave0 pipelined 2-deep flag poll, LDS fan-out ----
    if (m == 0) {
      const u32* fp = &g_done[h & (NREPF - 1)][0] + lane;
      // batch A in flight
      u32 c0 = __hip_atomic_load(fp,       __ATOMIC_RELAXED, __HIP_MEMORY_SCOPE_AGENT);
      u32 c1 = __hip_atomic_load(fp + 64,  __ATOMIC_RELAXED, __HIP_MEMORY_SCOPE_AGENT);
      u32 c2 = __hip_atomic_load(fp + 128, __ATOMIC_RELAXED, __HIP_MEMORY_SCOPE_AGENT);
      u32 c3 = __hip_atomic_load(fp + 192, __ATOMIC_RELAXED, __HIP_MEMORY_SCOPE_AGENT);
      for (;;) {
        // issue batch B before evaluating A
        const u32 d0 = __hip_atomic_load(fp,       __ATOMIC_RELAXED, __HIP_MEMORY_SCOPE_AGENT);
        const u32 d1 = __hip_atomic_load(fp + 64,  __ATOMIC_RELAXED, __HIP_MEMORY_SCOPE_AGENT);
        const u32 d2 = __hip_atomic_load(fp + 128, __ATOMIC_RELAXED, __HIP_MEMORY_SCOPE_AGENT);
        const u32 d3 = __hip_atomic_load(fp + 192, __ATOMIC_RELAXED, __HIP_MEMORY_SCOPE_AGENT);
        if (__all((c0 >= tgt) & (c1 >= tgt) & (c2 >= tgt) & (c3 >= tgt))) break;
        // issue batch A' before evaluating B
        c0 = __hip_atomic_load(fp,       __ATOMIC_RELAXED, __HIP_MEMORY_SCOPE_AGENT);
        c1 = __hip_atomic_load(fp + 64,  __ATOMIC_RELAXED, __HIP_MEMORY_SCOPE_AGENT);
        c2 = __hip_atomic_load(fp + 128, __ATOMIC_RELAXED, __HIP_MEMORY_SCOPE_AGENT);
        c3 = __hip_atomic_load(fp + 192, __ATOMIC_RELAXED, __HIP_MEMORY_SCOPE_AGENT);
        if (__all((d0 >= tgt) & (d1 >= tgt) & (d2 >= tgt) & (d3 >= tgt))) break;
      }
      if (lane == 0)
        __hip_atomic_store(&s_go, (u32)(t + 1), __ATOMIC_RELAXED,
                           __HIP_MEMORY_SCOPE_WORKGROUP);
    } else {
      // s_sleep frees SIMD issue slots for wave0's poll + stage issue
      while (__hip_atomic_load(&s_go, __ATOMIC_RELAXED,
                               __HIP_MEMORY_SCOPE_WORKGROUP) < (u32)(t + 1))
        __builtin_amdgcn_s_sleep(1);
    }
    asm volatile("" ::: "memory");

    // ---- stage (dense) + embedded-tag validation (flags are a hint) ----
    {
      const u64* src = g_hy + (size_t)t * NROW + tid;
      u64 a0 = __hip_atomic_load(src,        __ATOMIC_RELAXED, __HIP_MEMORY_SCOPE_AGENT);
      u64 a1 = __hip_atomic_load(src + 1024, __ATOMIC_RELAXED, __HIP_MEMORY_SCOPE_AGENT);
      u64 a2 = __hip_atomic_load(src + 2048, __ATOMIC_RELAXED, __HIP_MEMORY_SCOPE_AGENT);
      u64 a3 = __hip_atomic_load(src + 3072, __ATOMIC_RELAXED, __HIP_MEMORY_SCOPE_AGENT);
      while (!((((u32)(a0 >> 32)) >= tgt) & (((u32)(a1 >> 32)) >= tgt) &
               (((u32)(a2 >> 32)) >= tgt) & (((u32)(a3 >> 32)) >= tgt))) {
        __builtin_amdgcn_s_sleep(1);
        a0 = __hip_atomic_load(src,        __ATOMIC_RELAXED, __HIP_MEMORY_SCOPE_AGENT);
        a1 = __hip_atomic_load(src + 1024, __ATOMIC_RELAXED, __HIP_MEMORY_SCOPE_AGENT);
        a2 = __hip_atomic_load(src + 2048, __ATOMIC_RELAXED, __HIP_MEMORY_SCOPE_AGENT);
        a3 = __hip_atomic_load(src + 3072, __ATOMIC_RELAXED, __HIP_MEMORY_SCOPE_AGENT);
      }
      float* dst = &hy_lds[buf][0];
      // packet p = tid + 1024k: module = tid&15, column = hrow + 64k
      dst[mcol + hrow      ] = __uint_as_float((u32)a0);
      dst[mcol + hrow +  64] = __uint_as_float((u32)a1);
      dst[mcol + hrow + 128] = __uint_as_float((u32)a2);
      dst[mcol + hrow + 192] = __uint_as_float((u32)a3);
    }
    __syncthreads();   // ONLY barrier per step; prev publish ack drains here

    // input term (xd prefetched last iteration)
    float acc_o = win.x * (maskm * xd.x);
    acc_o = fmaf(win.y, maskm * xd.y, acc_o);
    // recurrent term
    {
      const f32x4 hp = *reinterpret_cast<const f32x4*>(&hy_lds[buf][m * HP + 4 * lane]);
      acc_o = fmaf(wrec.x, hp.x, acc_o);
      acc_o = fmaf(wrec.y, hp.y, acc_o);
      acc_o = fmaf(wrec.z, hp.z, acc_o);
      acc_o = fmaf(wrec.w, hp.w, acc_o);
    }
    // feedback: register weights x LDS hy fragments
    float acc_fb = 0.f;
#pragma unroll
    for (int k = 0; k < M; ++k) {
      if (k < ocnt) {
        const int o = s_olist[m][k];
        const f32x4 hp = *reinterpret_cast<const f32x4*>(&hy_lds[buf][o * HP + 4 * lane]);
        float po = wreg[k].x * hp.x;
        po = fmaf(wreg[k].y, hp.y, po);
        po = fmaf(wreg[k].z, hp.z, po);
        po = fmaf(wreg[k].w, hp.w, po);
        acc_fb += po;
      }
    }

    // wave-wide butterfly reduce
    for (int off = 32; off > 0; off >>= 1) {
      acc_fb += __shfl_xor(acc_fb, off);
      acc_o  += __shfl_xor(acc_o,  off);
    }

    if (lane == 0) {
      const float fb   = scal * acc_fb;
      const float hy_p = hy_lds[buf][m * HP + h];
      const float pre  = acc_o + biasv + fb;
      const float hz_n = hz + DT_C * (tanhf(pre) - GAMMA_C * hy_p - EPS_C * hz);
      const float hy_n = hy_p + DT_C * hz_n;
      hz = hz_n;
      // drop tagged packet in LDS; wave0 publishes the whole column
      const u64 pkt = ((u64)(tgt + 1u) << 32) | (u64)__float_as_uint(hy_n);
      __hip_atomic_store(&s_pub[m], pkt, __ATOMIC_RELAXED,
                         __HIP_MEMORY_SCOPE_WORKGROUP);
      // buffer hz/fb in LDS; flushed once after the loop
      outb_hz[t][m] = hz_n;
      outb_fb[t][m] = fb;
    }
    asm volatile("" ::: "memory");

    // ---- wave0: gather 16 packets, ONE coalesced store, then flags ----
    if (m == 0) {
      u64 p;
      for (;;) {
        p = __hip_atomic_load(&s_pub[lane & 15], __ATOMIC_RELAXED,
                              __HIP_MEMORY_SCOPE_WORKGROUP);
        if (__all(((u32)(p >> 32)) >= tgt + 1u)) break;
      }
      if (lane < M)
        __hip_atomic_store(&g_hy[(size_t)(t + 1) * NROW + (size_t)h * M + lane],
                           p, __ATOMIC_RELAXED, __HIP_MEMORY_SCOPE_AGENT);
      // replicated completion flags (hint; tags validated by consumers)
      if (lane < NREPF)
        __hip_atomic_store(&g_done[lane][h], tgt + 1u,
                           __ATOMIC_RELAXED, __HIP_MEMORY_SCOPE_AGENT);
    }

    if (t + 1 < T)
      xd = *reinterpret_cast<const float2*>(x + (size_t)(t + 1) * I + 2 * lane);
    buf ^= 1;
  }

  __syncthreads();   // outb_* visible; final publishes drained (vmcnt(0))

  // ---- one-time flush: hy from own g_hy slots, hz/fb from LDS ----
  const size_t fb_base = (size_t)T * M * 2 * H;
  for (int i = tid; i < T * M; i += NTHR) {
    const int t  = i >> 4;
    const int mm = i & 15;
    const u64 q = __hip_atomic_load(
        &g_hy[(size_t)(t + 1) * NROW + (size_t)h * M + mm],
        __ATOMIC_RELAXED, __HIP_MEMORY_SCOPE_AGENT);
    const float hyv = __uint_as_float((u32)q);
    const size_t so = (size_t)t * (M * 2 * H) + (size_t)mm * (2 * H);
    out[so + h]     = hyv;
    out[so + H + h] = outb_hz[t][mm];
    out[fb_base + (size_t)t * (M * H) + (size_t)mm * H + h] = outb_fb[t][mm];
  }

  // epoch bump for next launch/replay: strictly above every tag used here
  if (h == 0 && tid == 0)
    __hip_atomic_store(&g_epoch, base + (u32)(T + 2),
                       __ATOMIC_RELAXED, __HIP_MEMORY_SCOPE_AGENT);
}

extern "C" void kernel_launch(void* const* d_in, const int* in_sizes, int n_in,
                              void* d_out, int out_size, void* d_ws, size_t ws_size,
                              hipStream_t stream) {
  const float* x     = (const float*)d_in[0];
  const float* wm    = (const float*)d_in[1];
  const float* conn  = (const float*)d_in[2];
  const float* mask  = (const float*)d_in[3];
  const float* W_in  = (const float*)d_in[4];
  const float* W_rec = (const float*)d_in[5];
  const float* bias  = (const float*)d_in[6];

  rnn_persistent<<<NBLK, NTHR, 0, stream>>>(
      x, wm, conn, mask, W_in, W_rec, bias, (float*)d_out);
}

// Round 10
// 1054.150 us; speedup vs baseline: 1.3366x; 1.1270x over previous
//
#include <hip/hip_runtime.h>
#include <math.h>

// Archetipes RNN scan: T=256 sequential steps, M=16 modules, H=256, I=128.
// R18 = R14/R17 base + PER-GROUP pipelined detect+stage (same traffic,
// finer go-granularity). 2-deep poll dropped (R17: null).
// R17 post-mortem: detect micro-latency exonerated (1188 ~= R14's 1190).
// Flag-write serialization also debunked by arithmetic (16 writes/line
// spread over the whole step window). Revised residual: stage STAMPEDE --
// at last-flag time all 256 blocks fire 512 LLC line-reads each (131K
// requests, 8.4 MB in <1us); the tail block's staging queues behind all.
// Change: wave0's poll already holds all 256 flags as c0..c3, and each
// register maps 1:1 to one of the 4 stage loads (columns 0-63/64-127/
// 128-191/192-255 <-> src+0/+1024/+2048/+3072). So:
//  - wave0 evaluates groups independently, stores s_gog[k]=t+1 (LDS) as
//    each passes, and issues its OWN group-k load immediately;
//  - waves 1..15 spin per-group (LDS, s_sleep) and issue each load as its
//    group fires; validation + LDS writes deferred until all 4 issued
//    (loads stay in flight across LDS spins -- no vmcnt between issues).
// ~3/4 of staging issues during the flag-arrival window instead of one
// post-last-flag burst -> LLC queue tail shrinks; tail block unchanged
// (never worse). Embedded-tag retry stays ground truth -- no new ordering
// assumptions. Everything else byte-for-byte R14: replicated flag lines
// (plain stores, distinct addresses), coalesced column publish via s_pub
// (R12), padded LDS HP=260 (R10), dense staging (R9), weights register-
// resident (R3), conn-sparsity olist (R4), LDS out-buffer + single flush
// (R7), ONE barrier/step, epoch-monotone tags (graph-replay safe).

#define DT_C    0.042f
#define GAMMA_C 2.7f
#define EPS_C   4.7f

constexpr int M = 16, H = 256, I = 128, T = 256;
constexpr int HP = H + 4;     // padded LDS row stride (16B-aligned, 2-way banks)
constexpr int NROW = M * H;   // 4096 packets per slot
constexpr int NBLK = 256;
constexpr int NTHR = 1024;    // 16 waves
constexpr int NREPF = 16;     // flag replica arrays (1 KB each)

typedef float f32x4 __attribute__((ext_vector_type(4)));
typedef unsigned long long u64;
typedef unsigned int u32;

// Slot s (s=0..T) = hy after s steps. Packet = (tag<<32)|float_bits,
// tag = base + s + 1. Flat index p = h*16 + m.
__device__ __align__(64) u64 g_hy[(size_t)(T + 1) * NROW];   // 8.4 MB
__device__ __align__(64) u32 g_done[NREPF][NBLK];            // 16 x 1 KB
__device__ u32 g_epoch;

__global__ __launch_bounds__(NTHR) void rnn_persistent(
    const float* __restrict__ x,      // T*I
    const float* __restrict__ wm,     // M*M*H*H
    const float* __restrict__ conn,   // M*M
    const float* __restrict__ mask,   // M
    const float* __restrict__ W_in,   // M*H*I
    const float* __restrict__ W_rec,  // M*H*H
    const float* __restrict__ bias,   // M*H
    float* __restrict__ out)          // T*M*2*H state_seq, then T*M*H fb_seq
{
  const int h    = blockIdx.x;
  const int tid  = threadIdx.x;
  const int m    = tid >> 6;      // wave = module
  const int lane = tid & 63;

  __shared__ float hy_lds[2][M * HP];   // 2 x 16.25 KB, layout [m][h] padded
  __shared__ float outb_hz[T][M];       // 16 KB
  __shared__ float outb_fb[T][M];       // 16 KB
  __shared__ u64   s_pub[M];            // publish gather (tagged packets)
  __shared__ float s_c[M * M];
  __shared__ float s_scal[M];
  __shared__ int   s_olist[M][M];
  __shared__ float s_oc[M][M];
  __shared__ int   s_ocnt[M];
  __shared__ u32   s_base;
  __shared__ u32   s_gog[4];            // monotone per-group step flags

  if (tid == 0)
    s_base = __hip_atomic_load(&g_epoch, __ATOMIC_RELAXED, __HIP_MEMORY_SCOPE_AGENT);
  if (tid < 4) s_gog[tid] = 0;
  if (tid < M) s_pub[tid] = 0ull;
  if (tid < M * M) s_c[tid] = conn[tid];
  __syncthreads();

  // ---- publish slot 0 = zeros + flags ASAP (before heavy weight loads) ----
  const u32 base = s_base;
  if (tid < M) {
    const u64 pkt0 = ((u64)(base + 1u) << 32);   // hy = 0.0f, tag = base+1
    __hip_atomic_store(&g_hy[(size_t)h * M + tid], pkt0,
                       __ATOMIC_RELAXED, __HIP_MEMORY_SCOPE_AGENT);
  }
  if (tid < NREPF)
    __hip_atomic_store(&g_done[tid][h], base + 1u,
                       __ATOMIC_RELAXED, __HIP_MEMORY_SCOPE_AGENT);

  if (tid < M) {
    float s = 0.f; int cnt = 0;
    for (int o = 0; o < M; ++o) {
      float c = s_c[tid * M + o];
      s += c;
      if (c != 0.f) { s_olist[tid][cnt] = o; s_oc[tid][cnt] = c; ++cnt; }
    }
    for (int k = cnt; k < M; ++k) { s_olist[tid][k] = 0; s_oc[tid][k] = 0.f; }
    s_ocnt[tid] = cnt;
    s_scal[tid] = 1.0f / fmaxf(s, 1.0f);
  }
  __syncthreads();

  const int   rowg  = m * H + h;    // global row (bias/W_rec/W_in)
  const float maskm = mask[m];
  const float biasv = bias[rowg];
  const float scal  = s_scal[m];
  const int   ocnt  = s_ocnt[m];

  // ---- one-time: weights into registers (conn pre-applied) ----
  f32x4 wreg[M];
#pragma unroll
  for (int k = 0; k < M; ++k) {
    if (k < ocnt) {
      const int o = s_olist[m][k];
      const f32x4 wv = *reinterpret_cast<const f32x4*>(
          wm + ((size_t)(m * M + o) * H + h) * H + 4 * lane);
      wreg[k] = wv * s_oc[m][k];
    } else {
      wreg[k] = (f32x4)0.f;
    }
  }
  const f32x4  wrec = *reinterpret_cast<const f32x4*>(W_rec + (size_t)rowg * H + 4 * lane);
  const float2 win  = *reinterpret_cast<const float2*>(W_in + (size_t)rowg * I + 2 * lane);

  float hz = 0.f;
  // x[0] prefetch (per-lane slice; same for every wave)
  float2 xd = *reinterpret_cast<const float2*>(x + 2 * lane);

  const int  mcol = (tid & 15) * HP;   // staging LDS column base
  const int  hrow = tid >> 4;          // staging LDS row (0..63)
  int buf = 0;

  for (int t = 0; t < T; ++t) {
    const u32 tgt = base + (u32)t + 1u;
    const u64* src = g_hy + (size_t)t * NROW + tid;
    u64 a0 = 0, a1 = 0, a2 = 0, a3 = 0;

    // ---- per-group detect + pipelined stage issue ----
    if (m == 0) {
      // wave0: poll flags; as each 64-column group passes, publish s_gog
      // and issue own stage load for that group (stays in flight).
      const u32* fp = &g_done[h & (NREPF - 1)][0] + lane;
      u32 pend = 0xFu;
      do {
        const u32 c0 = __hip_atomic_load(fp,       __ATOMIC_RELAXED, __HIP_MEMORY_SCOPE_AGENT);
        const u32 c1 = __hip_atomic_load(fp + 64,  __ATOMIC_RELAXED, __HIP_MEMORY_SCOPE_AGENT);
        const u32 c2 = __hip_atomic_load(fp + 128, __ATOMIC_RELAXED, __HIP_MEMORY_SCOPE_AGENT);
        const u32 c3 = __hip_atomic_load(fp + 192, __ATOMIC_RELAXED, __HIP_MEMORY_SCOPE_AGENT);
        if ((pend & 1u) && __all(c0 >= tgt)) {
          if (lane == 0)
            __hip_atomic_store(&s_gog[0], (u32)(t + 1), __ATOMIC_RELAXED,
                               __HIP_MEMORY_SCOPE_WORKGROUP);
          a0 = __hip_atomic_load(src, __ATOMIC_RELAXED, __HIP_MEMORY_SCOPE_AGENT);
          pend &= ~1u;
        }
        if ((pend & 2u) && __all(c1 >= tgt)) {
          if (lane == 0)
            __hip_atomic_store(&s_gog[1], (u32)(t + 1), __ATOMIC_RELAXED,
                               __HIP_MEMORY_SCOPE_WORKGROUP);
          a1 = __hip_atomic_load(src + 1024, __ATOMIC_RELAXED, __HIP_MEMORY_SCOPE_AGENT);
          pend &= ~2u;
        }
        if ((pend & 4u) && __all(c2 >= tgt)) {
          if (lane == 0)
            __hip_atomic_store(&s_gog[2], (u32)(t + 1), __ATOMIC_RELAXED,
                               __HIP_MEMORY_SCOPE_WORKGROUP);
          a2 = __hip_atomic_load(src + 2048, __ATOMIC_RELAXED, __HIP_MEMORY_SCOPE_AGENT);
          pend &= ~4u;
        }
        if ((pend & 8u) && __all(c3 >= tgt)) {
          if (lane == 0)
            __hip_atomic_store(&s_gog[3], (u32)(t + 1), __ATOMIC_RELAXED,
                               __HIP_MEMORY_SCOPE_WORKGROUP);
          a3 = __hip_atomic_load(src + 3072, __ATOMIC_RELAXED, __HIP_MEMORY_SCOPE_AGENT);
          pend &= ~8u;
        }
      } while (pend);
    } else {
      // waves 1..15: per-group LDS spin, issue load as group fires.
      // Loads stay outstanding across spins (no vmem in the spin loops).
      while (__hip_atomic_load(&s_gog[0], __ATOMIC_RELAXED,
                               __HIP_MEMORY_SCOPE_WORKGROUP) < (u32)(t + 1))
        __builtin_amdgcn_s_sleep(1);
      a0 = __hip_atomic_load(src, __ATOMIC_RELAXED, __HIP_MEMORY_SCOPE_AGENT);
      while (__hip_atomic_load(&s_gog[1], __ATOMIC_RELAXED,
                               __HIP_MEMORY_SCOPE_WORKGROUP) < (u32)(t + 1))
        __builtin_amdgcn_s_sleep(1);
      a1 = __hip_atomic_load(src + 1024, __ATOMIC_RELAXED, __HIP_MEMORY_SCOPE_AGENT);
      while (__hip_atomic_load(&s_gog[2], __ATOMIC_RELAXED,
                               __HIP_MEMORY_SCOPE_WORKGROUP) < (u32)(t + 1))
        __builtin_amdgcn_s_sleep(1);
      a2 = __hip_atomic_load(src + 2048, __ATOMIC_RELAXED, __HIP_MEMORY_SCOPE_AGENT);
      while (__hip_atomic_load(&s_gog[3], __ATOMIC_RELAXED,
                               __HIP_MEMORY_SCOPE_WORKGROUP) < (u32)(t + 1))
        __builtin_amdgcn_s_sleep(1);
      a3 = __hip_atomic_load(src + 3072, __ATOMIC_RELAXED, __HIP_MEMORY_SCOPE_AGENT);
    }
    asm volatile("" ::: "memory");

    // ---- validate embedded tags (flags are a hint; rare retry) ----
    {
      while (!((((u32)(a0 >> 32)) >= tgt) & (((u32)(a1 >> 32)) >= tgt) &
               (((u32)(a2 >> 32)) >= tgt) & (((u32)(a3 >> 32)) >= tgt))) {
        __builtin_amdgcn_s_sleep(1);
        a0 = __hip_atomic_load(src,        __ATOMIC_RELAXED, __HIP_MEMORY_SCOPE_AGENT);
        a1 = __hip_atomic_load(src + 1024, __ATOMIC_RELAXED, __HIP_MEMORY_SCOPE_AGENT);
        a2 = __hip_atomic_load(src + 2048, __ATOMIC_RELAXED, __HIP_MEMORY_SCOPE_AGENT);
        a3 = __hip_atomic_load(src + 3072, __ATOMIC_RELAXED, __HIP_MEMORY_SCOPE_AGENT);
      }
      float* dst = &hy_lds[buf][0];
      // packet p = tid + 1024k: module = tid&15, column = hrow + 64k
      dst[mcol + hrow      ] = __uint_as_float((u32)a0);
      dst[mcol + hrow +  64] = __uint_as_float((u32)a1);
      dst[mcol + hrow + 128] = __uint_as_float((u32)a2);
      dst[mcol + hrow + 192] = __uint_as_float((u32)a3);
    }
    __syncthreads();   // ONLY barrier per step; prev publish ack drains here

    // input term (xd prefetched last iteration)
    float acc_o = win.x * (maskm * xd.x);
    acc_o = fmaf(win.y, maskm * xd.y, acc_o);
    // recurrent term
    {
      const f32x4 hp = *reinterpret_cast<const f32x4*>(&hy_lds[buf][m * HP + 4 * lane]);
      acc_o = fmaf(wrec.x, hp.x, acc_o);
      acc_o = fmaf(wrec.y, hp.y, acc_o);
      acc_o = fmaf(wrec.z, hp.z, acc_o);
      acc_o = fmaf(wrec.w, hp.w, acc_o);
    }
    // feedback: register weights x LDS hy fragments
    float acc_fb = 0.f;
#pragma unroll
    for (int k = 0; k < M; ++k) {
      if (k < ocnt) {
        const int o = s_olist[m][k];
        const f32x4 hp = *reinterpret_cast<const f32x4*>(&hy_lds[buf][o * HP + 4 * lane]);
        float po = wreg[k].x * hp.x;
        po = fmaf(wreg[k].y, hp.y, po);
        po = fmaf(wreg[k].z, hp.z, po);
        po = fmaf(wreg[k].w, hp.w, po);
        acc_fb += po;
      }
    }

    // wave-wide butterfly reduce
    for (int off = 32; off > 0; off >>= 1) {
      acc_fb += __shfl_xor(acc_fb, off);
      acc_o  += __shfl_xor(acc_o,  off);
    }

    if (lane == 0) {
      const float fb   = scal * acc_fb;
      const float hy_p = hy_lds[buf][m * HP + h];
      const float pre  = acc_o + biasv + fb;
      const float hz_n = hz + DT_C * (tanhf(pre) - GAMMA_C * hy_p - EPS_C * hz);
      const float hy_n = hy_p + DT_C * hz_n;
      hz = hz_n;
      // drop tagged packet in LDS; wave0 publishes the whole column
      const u64 pkt = ((u64)(tgt + 1u) << 32) | (u64)__float_as_uint(hy_n);
      __hip_atomic_store(&s_pub[m], pkt, __ATOMIC_RELAXED,
                         __HIP_MEMORY_SCOPE_WORKGROUP);
      // buffer hz/fb in LDS; flushed once after the loop
      outb_hz[t][m] = hz_n;
      outb_fb[t][m] = fb;
    }
    asm volatile("" ::: "memory");

    // ---- wave0: gather 16 packets, ONE coalesced store, then flags ----
    if (m == 0) {
      u64 p;
      for (;;) {
        p = __hip_atomic_load(&s_pub[lane & 15], __ATOMIC_RELAXED,
                              __HIP_MEMORY_SCOPE_WORKGROUP);
        if (__all(((u32)(p >> 32)) >= tgt + 1u)) break;
      }
      if (lane < M)
        __hip_atomic_store(&g_hy[(size_t)(t + 1) * NROW + (size_t)h * M + lane],
                           p, __ATOMIC_RELAXED, __HIP_MEMORY_SCOPE_AGENT);
      // replicated completion flags (hint; tags validated by consumers)
      if (lane < NREPF)
        __hip_atomic_store(&g_done[lane][h], tgt + 1u,
                           __ATOMIC_RELAXED, __HIP_MEMORY_SCOPE_AGENT);
    }

    if (t + 1 < T)
      xd = *reinterpret_cast<const float2*>(x + (size_t)(t + 1) * I + 2 * lane);
    buf ^= 1;
  }

  __syncthreads();   // outb_* visible; final publishes drained (vmcnt(0))

  // ---- one-time flush: hy from own g_hy slots, hz/fb from LDS ----
  const size_t fb_base = (size_t)T * M * 2 * H;
  for (int i = tid; i < T * M; i += NTHR) {
    const int t  = i >> 4;
    const int mm = i & 15;
    const u64 q = __hip_atomic_load(
        &g_hy[(size_t)(t + 1) * NROW + (size_t)h * M + mm],
        __ATOMIC_RELAXED, __HIP_MEMORY_SCOPE_AGENT);
    const float hyv = __uint_as_float((u32)q);
    const size_t so = (size_t)t * (M * 2 * H) + (size_t)mm * (2 * H);
    out[so + h]     = hyv;
    out[so + H + h] = outb_hz[t][mm];
    out[fb_base + (size_t)t * (M * H) + (size_t)mm * H + h] = outb_fb[t][mm];
  }

  // epoch bump for next launch/replay: strictly above every tag used here
  if (h == 0 && tid == 0)
    __hip_atomic_store(&g_epoch, base + (u32)(T + 2),
                       __ATOMIC_RELAXED, __HIP_MEMORY_SCOPE_AGENT);
}

extern "C" void kernel_launch(void* const* d_in, const int* in_sizes, int n_in,
                              void* d_out, int out_size, void* d_ws, size_t ws_size,
                              hipStream_t stream) {
  const float* x     = (const float*)d_in[0];
  const float* wm    = (const float*)d_in[1];
  const float* conn  = (const float*)d_in[2];
  const float* mask  = (const float*)d_in[3];
  const float* W_in  = (const float*)d_in[4];
  const float* W_rec = (const float*)d_in[5];
  const float* bias  = (const float*)d_in[6];

  rnn_persistent<<<NBLK, NTHR, 0, stream>>>(
      x, wm, conn, mask, W_in, W_rec, bias, (float*)d_out);
}